// Round 6
// baseline (1467.057 us; speedup 1.0000x reference)
//
#include <hip/hip_runtime.h>

#define NNODES 100000
#define NEDGES 800000
#define NTILE128 782            // ceil(100000/128)
#define NROWPAD (NTILE128*128)  // 100096 padded rows in ws planes

typedef __bf16 bf16x8 __attribute__((ext_vector_type(8)));
typedef float  f32x4  __attribute__((ext_vector_type(4)));

__device__ inline void split8(const float* s, bf16x8& h, bf16x8& l) {
#pragma unroll
    for (int j = 0; j < 8; ++j) {
        float v = s[j];
        __bf16 hh = (__bf16)v;
        h[j] = hh;
        l[j] = (__bf16)(v - (float)hh);
    }
}

// ===========================================================================
// CSR build (round-3 proven)
// ===========================================================================
__global__ __launch_bounds__(256) void hist_kernel(const int* __restrict__ dst,
                                                   int* __restrict__ counts, int nE) {
    int i = blockIdx.x * 256 + threadIdx.x;
    if (i < nE) atomicAdd(counts + dst[i], 1);
}

__global__ __launch_bounds__(256) void scan1_kernel(const int* __restrict__ counts,
                                                    int* __restrict__ bsum, int n) {
    __shared__ int s[256];
    int i = blockIdx.x * 256 + threadIdx.x;
    s[threadIdx.x] = (i < n) ? counts[i] : 0;
    __syncthreads();
    for (int off = 128; off > 0; off >>= 1) {
        if (threadIdx.x < off) s[threadIdx.x] += s[threadIdx.x + off];
        __syncthreads();
    }
    if (threadIdx.x == 0) bsum[blockIdx.x] = s[0];
}

__global__ __launch_bounds__(512) void scan2_kernel(int* __restrict__ bsum, int nb) {
    __shared__ int s[512];
    int t = threadIdx.x;
    int orig = (t < nb) ? bsum[t] : 0;
    s[t] = orig;
    __syncthreads();
    for (int off = 1; off < 512; off <<= 1) {
        int v = (t >= off) ? s[t - off] : 0;
        __syncthreads();
        s[t] += v;
        __syncthreads();
    }
    if (t < nb) bsum[t] = s[t] - orig;  // exclusive
}

__global__ __launch_bounds__(256) void scan3_kernel(int* __restrict__ counts,
                                                    const int* __restrict__ boff,
                                                    int* __restrict__ rowptr, int n) {
    __shared__ int s[256];
    int i = blockIdx.x * 256 + threadIdx.x;
    int t = threadIdx.x;
    int orig = (i < n) ? counts[i] : 0;
    s[t] = orig;
    __syncthreads();
    for (int off = 1; off < 256; off <<= 1) {
        int v = (t >= off) ? s[t - off] : 0;
        __syncthreads();
        s[t] += v;
        __syncthreads();
    }
    if (i < n) {
        rowptr[i] = boff[blockIdx.x] + s[t] - orig;
        counts[i] = 0;  // reused as fill cursor
    }
    if (i == n - 1) rowptr[n] = boff[blockIdx.x] + s[t];
}

__global__ __launch_bounds__(256) void fill_kernel(const int* __restrict__ src,
                                                   const int* __restrict__ dst,
                                                   const int* __restrict__ rowptr,
                                                   int* __restrict__ cur,
                                                   int* __restrict__ eidx, int nE) {
    int i = blockIdx.x * 256 + threadIdx.x;
    if (i >= nE) return;
    int d = dst[i];
    int p = atomicAdd(cur + d, 1);
    eidx[rowptr[d] + p] = src[i];
}

// ===========================================================================
// Gather-mean + combine (round-4 proven): out = base + mean_nbr hi(nbr)
// ===========================================================================
__global__ __launch_bounds__(256) void gather_kernel(const __bf16* __restrict__ Hhi,
                                                     const __bf16* __restrict__ Hlo,
                                                     const int* __restrict__ rowptr,
                                                     const int* __restrict__ eidx,
                                                     __bf16* __restrict__ Ohi,
                                                     __bf16* __restrict__ Olo, int n) {
    int node = blockIdx.x * 4 + (threadIdx.x >> 6);
    int lane = threadIdx.x & 63;
    if (node >= n) return;
    int g = lane >> 4, p = lane & 15;
    int e0 = rowptr[node], e1 = rowptr[node + 1];
    float acc[8] = {0.f, 0.f, 0.f, 0.f, 0.f, 0.f, 0.f, 0.f};
    for (int j = e0; j < e1; j += 4) {
        int na = e1 - j;
        int sid = (lane < na && lane < 4) ? eidx[j + lane] : -1;
        int s = __shfl(sid, g);
        if (s >= 0) {
            bf16x8 v = *(const bf16x8*)(Hhi + (size_t)s * 128 + p * 8);
#pragma unroll
            for (int r = 0; r < 8; ++r) acc[r] += (float)v[r];
        }
    }
#pragma unroll
    for (int r = 0; r < 8; ++r) {
        acc[r] += __shfl_xor(acc[r], 16);
        acc[r] += __shfl_xor(acc[r], 32);
    }
    if (g == 0) {
        float rinv = 1.0f / fmaxf((float)(e1 - e0), 1.0f);
        bf16x8 bh = *(const bf16x8*)(Hhi + (size_t)node * 128 + p * 8);
        bf16x8 bl = *(const bf16x8*)(Hlo + (size_t)node * 128 + p * 8);
        bf16x8 oh, ol;
#pragma unroll
        for (int r = 0; r < 8; ++r) {
            float v = (float)bh[r] + (float)bl[r] + acc[r] * rinv;
            __bf16 h = (__bf16)v;
            oh[r] = h;
            ol[r] = (__bf16)(v - (float)h);
        }
        *(bf16x8*)(Ohi + (size_t)node * 128 + p * 8) = oh;
        *(bf16x8*)(Olo + (size_t)node * 128 + p * 8) = ol;
    }
}

// ===========================================================================
// gemm2: out[M,N] = act(in[M,128] @ W[N,128]^T + b), N = T*16 (128 or 64).
// 512 thr = 8 waves; wave w owns rows [tile*128 + 16w, +16) x ALL N cols
// -> T independent MFMA chains per wave (ILP), no inter-wave exchange.
// W hi/lo split once per block into LDS, FRAG-PACKED: wf[plane][t][ks][lane]
// so each MFMA's W operand is one conflict-free ds_read_b128.
// 3-term split product (hi*hi + lo*hi + hi*lo). Frag maps per m89 (proven
// rounds 3-5). __launch_bounds__(512,4) -> VGPR<=128 -> 2 blocks/CU.
// INF32: clamp rows >= NNODES (pad tile). OUTF32: guard m < NNODES.
// ===========================================================================
template <int T, bool INF32, bool OUTF32, bool RELU>
__global__ __launch_bounds__(512, 4) void gemm2_kernel(const void* __restrict__ Ah_,
                                                       const void* __restrict__ Al_,
                                                       const float* __restrict__ Wg,
                                                       const float* __restrict__ Bg,
                                                       __bf16* __restrict__ Ohi,
                                                       __bf16* __restrict__ Olo,
                                                       float* __restrict__ Of32,
                                                       int ntiles) {
    __shared__ __align__(16) __bf16 wf[2][T][4][64][8];  // 64KB (T=8) / 32KB (T=4)
    const int tid = threadIdx.x;
    const int lane = tid & 63, w = tid >> 6;
    const int lm = lane & 15, g = lane >> 4;

    // ---- stage W (fp32) -> LDS hi/lo fragments ----
    for (int c = tid; c < T * 4 * 64; c += 512) {
        int t = c >> 8;
        int ks = (c >> 6) & 3;
        int ln = c & 63;
        int n = t * 16 + (ln & 15);
        int k0 = ks * 32 + (ln >> 4) * 8;
        const float* src = Wg + (size_t)n * 128 + k0;
        float tv[8];
        *(float4*)tv = *(const float4*)src;
        *(float4*)(tv + 4) = *(const float4*)(src + 4);
        bf16x8 h, l;
        split8(tv, h, l);
        *(bf16x8*)&wf[0][t][ks][ln][0] = h;
        *(bf16x8*)&wf[1][t][ks][ln][0] = l;
    }
    float bval[T];
#pragma unroll
    for (int t = 0; t < T; ++t) bval[t] = Bg[t * 16 + lm];
    __syncthreads();

    for (int tile = blockIdx.x; tile < ntiles; tile += gridDim.x) {
        const int arow = tile * 128 + w * 16 + lm;
        bf16x8 ah[4], al[4];
        if (INF32) {
            const float* base = (const float*)Ah_ + (size_t)min(arow, NNODES - 1) * 128;
#pragma unroll
            for (int ks = 0; ks < 4; ++ks) {
                float tv[8];
                *(float4*)tv = *(const float4*)(base + ks * 32 + g * 8);
                *(float4*)(tv + 4) = *(const float4*)(base + ks * 32 + g * 8 + 4);
                split8(tv, ah[ks], al[ks]);
            }
        } else {
            const __bf16* bh = (const __bf16*)Ah_ + (size_t)arow * 128;
            const __bf16* bl = (const __bf16*)Al_ + (size_t)arow * 128;
#pragma unroll
            for (int ks = 0; ks < 4; ++ks) {
                ah[ks] = *(const bf16x8*)(bh + ks * 32 + g * 8);
                al[ks] = *(const bf16x8*)(bl + ks * 32 + g * 8);
            }
        }

        f32x4 acc[T];
#pragma unroll
        for (int t = 0; t < T; ++t) acc[t] = (f32x4){bval[t], bval[t], bval[t], bval[t]};
#pragma unroll
        for (int t = 0; t < T; ++t) {
#pragma unroll
            for (int ks = 0; ks < 4; ++ks) {
                bf16x8 wh = *(const bf16x8*)&wf[0][t][ks][lane][0];
                bf16x8 wl = *(const bf16x8*)&wf[1][t][ks][lane][0];
                acc[t] = __builtin_amdgcn_mfma_f32_16x16x32_bf16(ah[ks], wh, acc[t], 0, 0, 0);
                acc[t] = __builtin_amdgcn_mfma_f32_16x16x32_bf16(al[ks], wh, acc[t], 0, 0, 0);
                acc[t] = __builtin_amdgcn_mfma_f32_16x16x32_bf16(ah[ks], wl, acc[t], 0, 0, 0);
            }
        }

        const int mrow0 = tile * 128 + w * 16 + g * 4;
#pragma unroll
        for (int t = 0; t < T; ++t) {
            const int n = t * 16 + lm;
#pragma unroll
            for (int r = 0; r < 4; ++r) {
                float v = acc[t][r];
                if (RELU) v = fmaxf(v, 0.f);
                if (OUTF32) {
                    int m = mrow0 + r;
                    if (m < NNODES) Of32[(size_t)m * 64 + n] = v;
                } else {
                    __bf16 h = (__bf16)v;
                    Ohi[(size_t)(mrow0 + r) * 128 + n] = h;
                    Olo[(size_t)(mrow0 + r) * 128 + n] = (__bf16)(v - (float)h);
                }
            }
        }
    }
}

// ===========================================================================
extern "C" void kernel_launch(void* const* d_in, const int* in_sizes, int n_in,
                              void* d_out, int out_size, void* d_ws, size_t ws_size,
                              hipStream_t stream) {
    const float* x   = (const float*)d_in[0];
    const int*   src = (const int*)d_in[1];
    const int*   dst = (const int*)d_in[2];
    const float* W1  = (const float*)d_in[3];
    const float* b1  = (const float*)d_in[4];
    const float* W2  = (const float*)d_in[5];
    const float* b2  = (const float*)d_in[6];
    const float* W3  = (const float*)d_in[7];
    const float* b3  = (const float*)d_in[8];
    const float* Wo1 = (const float*)d_in[9];
    const float* bo1 = (const float*)d_in[10];
    const float* Wo2 = (const float*)d_in[11];
    const float* bo2 = (const float*)d_in[12];
    float* out = (float*)d_out;

    const size_t PLANE = (size_t)NROWPAD * 128 * sizeof(__bf16);  // 25.62 MB
    char* ws = (char*)d_ws;
    __bf16* P0h = (__bf16*)ws;
    __bf16* P0l = (__bf16*)(ws + PLANE);
    __bf16* P1h = (__bf16*)(ws + 2 * PLANE);
    __bf16* P1l = (__bf16*)(ws + 3 * PLANE);
    char* p = ws + 4 * PLANE;
    int* counts = (int*)p;  p += 512 * 1024;
    int* rowptr = (int*)p;  p += 512 * 1024;
    int* bsum   = (int*)p;  p += 16 * 1024;
    int* eidx   = (int*)p;  // 3.2 MB

    dim3 blk(256);
    const int NB = (NNODES + 255) / 256;  // 391
    const int ge = (NEDGES + 255) / 256;  // 3125
    const int gg = (NNODES + 3) / 4;      // 25000
    const int GG = 512;                   // gemm2 grid: 2 blocks/CU

    // ---- CSR build (dst-indexed) ----
    hipMemsetAsync(counts, 0, NNODES * sizeof(int), stream);
    hist_kernel<<<ge, blk, 0, stream>>>(dst, counts, NEDGES);
    scan1_kernel<<<NB, blk, 0, stream>>>(counts, bsum, NNODES);
    scan2_kernel<<<1, 512, 0, stream>>>(bsum, NB);
    scan3_kernel<<<NB, blk, 0, stream>>>(counts, bsum, rowptr, NNODES);
    fill_kernel<<<ge, blk, 0, stream>>>(src, dst, rowptr, counts, eidx, NEDGES);

    // ---- x2 = lin2(relu(lin1(x))) ----
    gemm2_kernel<8, true,  false, true ><<<GG, 512, 0, stream>>>(x, nullptr, W1, b1, P0h, P0l, nullptr, NTILE128);
    gemm2_kernel<8, false, false, false><<<GG, 512, 0, stream>>>(P0h, P0l, W2, b2, P1h, P1l, nullptr, NTILE128);

    // ---- h = x2 + mean_agg(x2) ----
    gather_kernel<<<gg, blk, 0, stream>>>(P1h, P1l, rowptr, eidx, P0h, P0l, NNODES);

    // ---- h = lin2(relu(lin1(h))); h3 = relu(lin3(h)) ----
    gemm2_kernel<8, false, false, true ><<<GG, 512, 0, stream>>>(P0h, P0l, W1, b1, P1h, P1l, nullptr, NTILE128);
    gemm2_kernel<8, false, false, false><<<GG, 512, 0, stream>>>(P1h, P1l, W2, b2, P0h, P0l, nullptr, NTILE128);
    gemm2_kernel<8, false, false, true ><<<GG, 512, 0, stream>>>(P0h, P0l, W3, b3, P1h, P1l, nullptr, NTILE128);

    // ---- h4 = h3 + mean_agg(h3) ----
    gather_kernel<<<gg, blk, 0, stream>>>(P1h, P1l, rowptr, eidx, P0h, P0l, NNODES);

    // ---- h5 = relu(lin3(h4)); h6 = relu(lino1(h5)); out = lino2(h6) ----
    gemm2_kernel<8, false, false, true ><<<GG, 512, 0, stream>>>(P0h, P0l, W3, b3, P1h, P1l, nullptr, NTILE128);
    gemm2_kernel<8, false, false, true ><<<GG, 512, 0, stream>>>(P1h, P1l, Wo1, bo1, P0h, P0l, nullptr, NTILE128);
    gemm2_kernel<4, false, true,  false><<<GG, 512, 0, stream>>>(P0h, P0l, Wo2, bo2, nullptr, nullptr, out, NTILE128);
}

// Round 7
// 502.087 us; speedup vs baseline: 2.9219x; 2.9219x over previous
//
#include <hip/hip_runtime.h>

#define NNODES 100000
#define NEDGES 800000
#define NTILE128 782            // ceil(100000/128)
#define NROWPAD (NTILE128*128)  // 100096 padded rows in ws planes

typedef __bf16 bf16x8 __attribute__((ext_vector_type(8)));
typedef float  f32x4  __attribute__((ext_vector_type(4)));
typedef unsigned int u32;

__device__ inline void split8(const float* s, bf16x8& h, bf16x8& l) {
#pragma unroll
    for (int j = 0; j < 8; ++j) {
        float v = s[j];
        __bf16 hh = (__bf16)v;
        h[j] = hh;
        l[j] = (__bf16)(v - (float)hh);
    }
}

// ===========================================================================
// CSR build (round-3 proven)
// ===========================================================================
__global__ __launch_bounds__(256) void hist_kernel(const int* __restrict__ dst,
                                                   int* __restrict__ counts, int nE) {
    int i = blockIdx.x * 256 + threadIdx.x;
    if (i < nE) atomicAdd(counts + dst[i], 1);
}

__global__ __launch_bounds__(256) void scan1_kernel(const int* __restrict__ counts,
                                                    int* __restrict__ bsum, int n) {
    __shared__ int s[256];
    int i = blockIdx.x * 256 + threadIdx.x;
    s[threadIdx.x] = (i < n) ? counts[i] : 0;
    __syncthreads();
    for (int off = 128; off > 0; off >>= 1) {
        if (threadIdx.x < off) s[threadIdx.x] += s[threadIdx.x + off];
        __syncthreads();
    }
    if (threadIdx.x == 0) bsum[blockIdx.x] = s[0];
}

__global__ __launch_bounds__(512) void scan2_kernel(int* __restrict__ bsum, int nb) {
    __shared__ int s[512];
    int t = threadIdx.x;
    int orig = (t < nb) ? bsum[t] : 0;
    s[t] = orig;
    __syncthreads();
    for (int off = 1; off < 512; off <<= 1) {
        int v = (t >= off) ? s[t - off] : 0;
        __syncthreads();
        s[t] += v;
        __syncthreads();
    }
    if (t < nb) bsum[t] = s[t] - orig;  // exclusive
}

__global__ __launch_bounds__(256) void scan3_kernel(int* __restrict__ counts,
                                                    const int* __restrict__ boff,
                                                    int* __restrict__ rowptr, int n) {
    __shared__ int s[256];
    int i = blockIdx.x * 256 + threadIdx.x;
    int t = threadIdx.x;
    int orig = (i < n) ? counts[i] : 0;
    s[t] = orig;
    __syncthreads();
    for (int off = 1; off < 256; off <<= 1) {
        int v = (t >= off) ? s[t - off] : 0;
        __syncthreads();
        s[t] += v;
        __syncthreads();
    }
    if (i < n) {
        rowptr[i] = boff[blockIdx.x] + s[t] - orig;
        counts[i] = 0;  // reused as fill cursor
    }
    if (i == n - 1) rowptr[n] = boff[blockIdx.x] + s[t];
}

__global__ __launch_bounds__(256) void fill_kernel(const int* __restrict__ src,
                                                   const int* __restrict__ dst,
                                                   const int* __restrict__ rowptr,
                                                   int* __restrict__ cur,
                                                   int* __restrict__ eidx, int nE) {
    int i = blockIdx.x * 256 + threadIdx.x;
    if (i >= nE) return;
    int d = dst[i];
    int p = atomicAdd(cur + d, 1);
    eidx[rowptr[d] + p] = src[i];
}

// ===========================================================================
// Gather-mean + combine (round-4 proven): out = base + mean_nbr hi(nbr)
// ===========================================================================
__global__ __launch_bounds__(256) void gather_kernel(const __bf16* __restrict__ Hhi,
                                                     const __bf16* __restrict__ Hlo,
                                                     const int* __restrict__ rowptr,
                                                     const int* __restrict__ eidx,
                                                     __bf16* __restrict__ Ohi,
                                                     __bf16* __restrict__ Olo, int n) {
    int node = blockIdx.x * 4 + (threadIdx.x >> 6);
    int lane = threadIdx.x & 63;
    if (node >= n) return;
    int g = lane >> 4, p = lane & 15;
    int e0 = rowptr[node], e1 = rowptr[node + 1];
    float acc[8] = {0.f, 0.f, 0.f, 0.f, 0.f, 0.f, 0.f, 0.f};
    for (int j = e0; j < e1; j += 4) {
        int na = e1 - j;
        int sid = (lane < na && lane < 4) ? eidx[j + lane] : -1;
        int s = __shfl(sid, g);
        if (s >= 0) {
            bf16x8 v = *(const bf16x8*)(Hhi + (size_t)s * 128 + p * 8);
#pragma unroll
            for (int r = 0; r < 8; ++r) acc[r] += (float)v[r];
        }
    }
#pragma unroll
    for (int r = 0; r < 8; ++r) {
        acc[r] += __shfl_xor(acc[r], 16);
        acc[r] += __shfl_xor(acc[r], 32);
    }
    if (g == 0) {
        float rinv = 1.0f / fmaxf((float)(e1 - e0), 1.0f);
        bf16x8 bh = *(const bf16x8*)(Hhi + (size_t)node * 128 + p * 8);
        bf16x8 bl = *(const bf16x8*)(Hlo + (size_t)node * 128 + p * 8);
        bf16x8 oh, ol;
#pragma unroll
        for (int r = 0; r < 8; ++r) {
            float v = (float)bh[r] + (float)bl[r] + acc[r] * rinv;
            __bf16 h = (__bf16)v;
            oh[r] = h;
            ol[r] = (__bf16)(v - (float)h);
        }
        *(bf16x8*)(Ohi + (size_t)node * 128 + p * 8) = oh;
        *(bf16x8*)(Olo + (size_t)node * 128 + p * 8) = ol;
    }
}

// ===========================================================================
// gemm3: out[M,N] = act(in[M,128] @ W[N,128]^T + b), N = T*16 (128 or 64).
// One-shot blocks: grid = NTILE128, block owns rows [bid*128, +128).
// 512 thr = 8 waves; wave w owns rows [+16w, +16) x ALL N cols (T chains ILP).
// W hi/lo split once into LDS fragpack (round-6 proven, 0 conflicts).
// EPILOGUE FIX (round-6 pathology): no scattered 2B stores. After last MFMA,
// reuse W-LDS as obuf[128][132] u32 = (lo16|hi16) packed per element; then
// cooperative readback writes both planes as full-line bf16x8 stores
// (per wave-instruction: 4 rows x 256B contiguous).
// OUTF32 epilogue already writes full 64B lines -> direct.
// 3-term split product; frag maps per m89 (proven rounds 3-6).
// ===========================================================================
template <int T, bool INF32, bool OUTF32, bool RELU>
__global__ __launch_bounds__(512, 4) void gemm3_kernel(const void* __restrict__ Ah_,
                                                       const void* __restrict__ Al_,
                                                       const float* __restrict__ Wg,
                                                       const float* __restrict__ Bg,
                                                       __bf16* __restrict__ Ohi,
                                                       __bf16* __restrict__ Olo,
                                                       float* __restrict__ Of32) {
    constexpr int WFB = 2 * T * 4 * 64 * 8 * 2;               // wf bytes (64KB @ T=8)
    constexpr int SMB = OUTF32 ? WFB : (WFB > 128 * 132 * 4 ? WFB : 128 * 132 * 4);
    __shared__ __align__(16) char smem[SMB];
    __bf16 (*wf)[T][4][64][8] = (__bf16(*)[T][4][64][8])smem;  // [plane][t][ks][lane][8]
    u32* obuf = (u32*)smem;                                     // [128][132] aliased

    const int tid = threadIdx.x;
    const int lane = tid & 63, w = tid >> 6;
    const int lm = lane & 15, g = lane >> 4;
    const int tile = blockIdx.x;

    // ---- stage W (fp32) -> LDS hi/lo fragments ----
    for (int c = tid; c < T * 4 * 64; c += 512) {
        int t = c >> 8;
        int ks = (c >> 6) & 3;
        int ln = c & 63;
        int n = t * 16 + (ln & 15);
        int k0 = ks * 32 + (ln >> 4) * 8;
        const float* srcp = Wg + (size_t)n * 128 + k0;
        float tv[8];
        *(float4*)tv = *(const float4*)srcp;
        *(float4*)(tv + 4) = *(const float4*)(srcp + 4);
        bf16x8 h, l;
        split8(tv, h, l);
        *(bf16x8*)&wf[0][t][ks][ln][0] = h;
        *(bf16x8*)&wf[1][t][ks][ln][0] = l;
    }
    float bval[T];
#pragma unroll
    for (int t = 0; t < T; ++t) bval[t] = Bg[t * 16 + lm];
    __syncthreads();

    // ---- A fragments (coalesced 16B loads; round-6 proven) ----
    const int arow = tile * 128 + w * 16 + lm;
    bf16x8 ah[4], al[4];
    if (INF32) {
        const float* base = (const float*)Ah_ + (size_t)min(arow, NNODES - 1) * 128;
#pragma unroll
        for (int ks = 0; ks < 4; ++ks) {
            float tv[8];
            *(float4*)tv = *(const float4*)(base + ks * 32 + g * 8);
            *(float4*)(tv + 4) = *(const float4*)(base + ks * 32 + g * 8 + 4);
            split8(tv, ah[ks], al[ks]);
        }
    } else {
        const __bf16* bh = (const __bf16*)Ah_ + (size_t)arow * 128;
        const __bf16* bl = (const __bf16*)Al_ + (size_t)arow * 128;
#pragma unroll
        for (int ks = 0; ks < 4; ++ks) {
            ah[ks] = *(const bf16x8*)(bh + ks * 32 + g * 8);
            al[ks] = *(const bf16x8*)(bl + ks * 32 + g * 8);
        }
    }

    // ---- MFMA: T independent chains ----
    f32x4 acc[T];
#pragma unroll
    for (int t = 0; t < T; ++t) acc[t] = (f32x4){bval[t], bval[t], bval[t], bval[t]};
#pragma unroll
    for (int t = 0; t < T; ++t) {
#pragma unroll
        for (int ks = 0; ks < 4; ++ks) {
            bf16x8 wh = *(const bf16x8*)&wf[0][t][ks][lane][0];
            bf16x8 wl = *(const bf16x8*)&wf[1][t][ks][lane][0];
            acc[t] = __builtin_amdgcn_mfma_f32_16x16x32_bf16(ah[ks], wh, acc[t], 0, 0, 0);
            acc[t] = __builtin_amdgcn_mfma_f32_16x16x32_bf16(al[ks], wh, acc[t], 0, 0, 0);
            acc[t] = __builtin_amdgcn_mfma_f32_16x16x32_bf16(ah[ks], wl, acc[t], 0, 0, 0);
        }
    }

    if (OUTF32) {
        // direct f32 stores: per (t,r) instruction = 4 rows x 64B full lines
        const int mrow0 = tile * 128 + w * 16 + g * 4;
#pragma unroll
        for (int t = 0; t < T; ++t) {
            const int n = t * 16 + lm;
#pragma unroll
            for (int r = 0; r < 4; ++r) {
                float v = acc[t][r];
                if (RELU) v = fmaxf(v, 0.f);
                int m = mrow0 + r;
                if (m < NNODES) Of32[(size_t)m * 64 + n] = v;
            }
        }
        return;
    }

    // ---- staged epilogue: acc -> obuf (u32 packed) -> full-line plane stores
    __syncthreads();  // all waves done with wf before alias
    {
        const int lrow0 = w * 16 + g * 4;
#pragma unroll
        for (int t = 0; t < T; ++t) {
            const int col = t * 16 + lm;
#pragma unroll
            for (int r = 0; r < 4; ++r) {
                float v = acc[t][r];
                if (RELU) v = fmaxf(v, 0.f);
                __bf16 h = (__bf16)v;
                __bf16 l = (__bf16)(v - (float)h);
                unsigned short hs = *(unsigned short*)&h;
                unsigned short ls = *(unsigned short*)&l;
                obuf[(lrow0 + r) * 132 + col] = ((u32)ls << 16) | (u32)hs;
            }
        }
    }
    __syncthreads();
#pragma unroll
    for (int pass = 0; pass < 4; ++pass) {
        int unit = pass * 512 + tid;   // 0..2047
        int lrow = unit >> 4;          // 0..127
        int c8 = unit & 15;            // 16B chunk (8 cols)
        const u32* p = obuf + lrow * 132 + c8 * 8;
        u32 v[8];
        *(f32x4*)v = *(const f32x4*)p;           // reinterpret 16B LDS reads
        *(f32x4*)(v + 4) = *(const f32x4*)(p + 4);
        bf16x8 hh, ll;
#pragma unroll
        for (int j = 0; j < 8; ++j) {
            unsigned short hs = (unsigned short)(v[j] & 0xffffu);
            unsigned short ls = (unsigned short)(v[j] >> 16);
            hh[j] = *(__bf16*)&hs;
            ll[j] = *(__bf16*)&ls;
        }
        size_t off = (size_t)(tile * 128 + lrow) * 128 + c8 * 8;
        *(bf16x8*)(Ohi + off) = hh;
        *(bf16x8*)(Olo + off) = ll;
    }
}

// ===========================================================================
extern "C" void kernel_launch(void* const* d_in, const int* in_sizes, int n_in,
                              void* d_out, int out_size, void* d_ws, size_t ws_size,
                              hipStream_t stream) {
    const float* x   = (const float*)d_in[0];
    const int*   src = (const int*)d_in[1];
    const int*   dst = (const int*)d_in[2];
    const float* W1  = (const float*)d_in[3];
    const float* b1  = (const float*)d_in[4];
    const float* W2  = (const float*)d_in[5];
    const float* b2  = (const float*)d_in[6];
    const float* W3  = (const float*)d_in[7];
    const float* b3  = (const float*)d_in[8];
    const float* Wo1 = (const float*)d_in[9];
    const float* bo1 = (const float*)d_in[10];
    const float* Wo2 = (const float*)d_in[11];
    const float* bo2 = (const float*)d_in[12];
    float* out = (float*)d_out;

    const size_t PLANE = (size_t)NROWPAD * 128 * sizeof(__bf16);  // 25.62 MB
    char* ws = (char*)d_ws;
    __bf16* P0h = (__bf16*)ws;
    __bf16* P0l = (__bf16*)(ws + PLANE);
    __bf16* P1h = (__bf16*)(ws + 2 * PLANE);
    __bf16* P1l = (__bf16*)(ws + 3 * PLANE);
    char* p = ws + 4 * PLANE;
    int* counts = (int*)p;  p += 512 * 1024;
    int* rowptr = (int*)p;  p += 512 * 1024;
    int* bsum   = (int*)p;  p += 16 * 1024;
    int* eidx   = (int*)p;  // 3.2 MB

    dim3 blk(256);
    const int NB = (NNODES + 255) / 256;  // 391
    const int ge = (NEDGES + 255) / 256;  // 3125
    const int gg = (NNODES + 3) / 4;      // 25000

    // ---- CSR build (dst-indexed) ----
    hipMemsetAsync(counts, 0, NNODES * sizeof(int), stream);
    hist_kernel<<<ge, blk, 0, stream>>>(dst, counts, NEDGES);
    scan1_kernel<<<NB, blk, 0, stream>>>(counts, bsum, NNODES);
    scan2_kernel<<<1, 512, 0, stream>>>(bsum, NB);
    scan3_kernel<<<NB, blk, 0, stream>>>(counts, bsum, rowptr, NNODES);
    fill_kernel<<<ge, blk, 0, stream>>>(src, dst, rowptr, counts, eidx, NEDGES);

    // ---- x2 = lin2(relu(lin1(x))) ----
    gemm3_kernel<8, true,  false, true ><<<NTILE128, 512, 0, stream>>>(x, nullptr, W1, b1, P0h, P0l, nullptr);
    gemm3_kernel<8, false, false, false><<<NTILE128, 512, 0, stream>>>(P0h, P0l, W2, b2, P1h, P1l, nullptr);

    // ---- h = x2 + mean_agg(x2) ----
    gather_kernel<<<gg, blk, 0, stream>>>(P1h, P1l, rowptr, eidx, P0h, P0l, NNODES);

    // ---- h = lin2(relu(lin1(h))); h3 = relu(lin3(h)) ----
    gemm3_kernel<8, false, false, true ><<<NTILE128, 512, 0, stream>>>(P0h, P0l, W1, b1, P1h, P1l, nullptr);
    gemm3_kernel<8, false, false, false><<<NTILE128, 512, 0, stream>>>(P1h, P1l, W2, b2, P0h, P0l, nullptr);
    gemm3_kernel<8, false, false, true ><<<NTILE128, 512, 0, stream>>>(P0h, P0l, W3, b3, P1h, P1l, nullptr);

    // ---- h4 = h3 + mean_agg(h3) ----
    gather_kernel<<<gg, blk, 0, stream>>>(P1h, P1l, rowptr, eidx, P0h, P0l, NNODES);

    // ---- h5 = relu(lin3(h4)); h6 = relu(lino1(h5)); out = lino2(h6) ----
    gemm3_kernel<8, false, false, true ><<<NTILE128, 512, 0, stream>>>(P0h, P0l, W3, b3, P1h, P1l, nullptr);
    gemm3_kernel<8, false, false, true ><<<NTILE128, 512, 0, stream>>>(P1h, P1l, Wo1, bo1, P0h, P0l, nullptr);
    gemm3_kernel<4, false, true,  false><<<NTILE128, 512, 0, stream>>>(P0h, P0l, Wo2, bo2, nullptr, nullptr, out);
}

// Round 8
// 498.146 us; speedup vs baseline: 2.9450x; 1.0079x over previous
//
#include <hip/hip_runtime.h>

#define NNODES 100000
#define NEDGES 800000
#define NTILE128 782            // ceil(100000/128)
#define NROWPAD (NTILE128*128)  // 100096 padded rows in ws planes

typedef __bf16 bf16x8 __attribute__((ext_vector_type(8)));
typedef float  f32x4  __attribute__((ext_vector_type(4)));
typedef unsigned int u32;

__device__ inline void split8(const float* s, bf16x8& h, bf16x8& l) {
#pragma unroll
    for (int j = 0; j < 8; ++j) {
        float v = s[j];
        __bf16 hh = (__bf16)v;
        h[j] = hh;
        l[j] = (__bf16)(v - (float)hh);
    }
}

// ===========================================================================
// CSR build (round-3 proven)
// ===========================================================================
__global__ __launch_bounds__(256) void hist_kernel(const int* __restrict__ dst,
                                                   int* __restrict__ counts, int nE) {
    int i = blockIdx.x * 256 + threadIdx.x;
    if (i < nE) atomicAdd(counts + dst[i], 1);
}

__global__ __launch_bounds__(256) void scan1_kernel(const int* __restrict__ counts,
                                                    int* __restrict__ bsum, int n) {
    __shared__ int s[256];
    int i = blockIdx.x * 256 + threadIdx.x;
    s[threadIdx.x] = (i < n) ? counts[i] : 0;
    __syncthreads();
    for (int off = 128; off > 0; off >>= 1) {
        if (threadIdx.x < off) s[threadIdx.x] += s[threadIdx.x + off];
        __syncthreads();
    }
    if (threadIdx.x == 0) bsum[blockIdx.x] = s[0];
}

__global__ __launch_bounds__(512) void scan2_kernel(int* __restrict__ bsum, int nb) {
    __shared__ int s[512];
    int t = threadIdx.x;
    int orig = (t < nb) ? bsum[t] : 0;
    s[t] = orig;
    __syncthreads();
    for (int off = 1; off < 512; off <<= 1) {
        int v = (t >= off) ? s[t - off] : 0;
        __syncthreads();
        s[t] += v;
        __syncthreads();
    }
    if (t < nb) bsum[t] = s[t] - orig;  // exclusive
}

__global__ __launch_bounds__(256) void scan3_kernel(int* __restrict__ counts,
                                                    const int* __restrict__ boff,
                                                    int* __restrict__ rowptr, int n) {
    __shared__ int s[256];
    int i = blockIdx.x * 256 + threadIdx.x;
    int t = threadIdx.x;
    int orig = (i < n) ? counts[i] : 0;
    s[t] = orig;
    __syncthreads();
    for (int off = 1; off < 256; off <<= 1) {
        int v = (t >= off) ? s[t - off] : 0;
        __syncthreads();
        s[t] += v;
        __syncthreads();
    }
    if (i < n) {
        rowptr[i] = boff[blockIdx.x] + s[t] - orig;
        counts[i] = 0;  // reused as fill cursor
    }
    if (i == n - 1) rowptr[n] = boff[blockIdx.x] + s[t];
}

__global__ __launch_bounds__(256) void fill_kernel(const int* __restrict__ src,
                                                   const int* __restrict__ dst,
                                                   const int* __restrict__ rowptr,
                                                   int* __restrict__ cur,
                                                   int* __restrict__ eidx, int nE) {
    int i = blockIdx.x * 256 + threadIdx.x;
    if (i >= nE) return;
    int d = dst[i];
    int p = atomicAdd(cur + d, 1);
    eidx[rowptr[d] + p] = src[i];
}

// ===========================================================================
// Gather-mean + combine: out = base + mean_nbr hi(nbr), re-split to hi/lo.
// One wave/node; ROUND-8: 8 edges in flight (two 4-edge batches issued
// back-to-back before accumulating) to halve serial latency rounds.
// 16 lanes x bf16x8 cover one 256B row per edge slot.
// ===========================================================================
__global__ __launch_bounds__(256) void gather_kernel(const __bf16* __restrict__ Hhi,
                                                     const __bf16* __restrict__ Hlo,
                                                     const int* __restrict__ rowptr,
                                                     const int* __restrict__ eidx,
                                                     __bf16* __restrict__ Ohi,
                                                     __bf16* __restrict__ Olo, int n) {
    int node = blockIdx.x * 4 + (threadIdx.x >> 6);
    int lane = threadIdx.x & 63;
    if (node >= n) return;
    int g = lane >> 4, p = lane & 15;
    int e0 = rowptr[node], e1 = rowptr[node + 1];
    float acc[8] = {0.f, 0.f, 0.f, 0.f, 0.f, 0.f, 0.f, 0.f};
    for (int j = e0; j < e1; j += 8) {
        int na = e1 - j;
        int sid = (lane < 8 && lane < na) ? eidx[j + lane] : -1;
        int s0 = __shfl(sid, g);        // edge slot g
        int s1 = __shfl(sid, g + 4);    // edge slot g+4
        bf16x8 v0, v1;
        bool h0 = (s0 >= 0), h1 = (s1 >= 0);
        if (h0) v0 = *(const bf16x8*)(Hhi + (size_t)s0 * 128 + p * 8);
        if (h1) v1 = *(const bf16x8*)(Hhi + (size_t)s1 * 128 + p * 8);
        if (h0) {
#pragma unroll
            for (int r = 0; r < 8; ++r) acc[r] += (float)v0[r];
        }
        if (h1) {
#pragma unroll
            for (int r = 0; r < 8; ++r) acc[r] += (float)v1[r];
        }
    }
#pragma unroll
    for (int r = 0; r < 8; ++r) {
        acc[r] += __shfl_xor(acc[r], 16);
        acc[r] += __shfl_xor(acc[r], 32);
    }
    if (g == 0) {
        float rinv = 1.0f / fmaxf((float)(e1 - e0), 1.0f);
        bf16x8 bh = *(const bf16x8*)(Hhi + (size_t)node * 128 + p * 8);
        bf16x8 bl = *(const bf16x8*)(Hlo + (size_t)node * 128 + p * 8);
        bf16x8 oh, ol;
#pragma unroll
        for (int r = 0; r < 8; ++r) {
            float v = (float)bh[r] + (float)bl[r] + acc[r] * rinv;
            __bf16 h = (__bf16)v;
            oh[r] = h;
            ol[r] = (__bf16)(v - (float)h);
        }
        *(bf16x8*)(Ohi + (size_t)node * 128 + p * 8) = oh;
        *(bf16x8*)(Olo + (size_t)node * 128 + p * 8) = ol;
    }
}

// ===========================================================================
// gemm3: out[M,N] = act(in[M,128] @ W[N,128]^T + b), N = T*16 (128 or 64).
// One-shot blocks: grid = NTILE128; 512 thr = 8 waves; wave w owns rows
// [tile*128+16w, +16) x ALL N cols (T independent MFMA chains).
// W hi/lo in LDS fragpack (round-6 proven, 0 conflicts); staged epilogue
// through aliased obuf -> full-line plane stores (round-7 proven).
// ROUND-8: A-fragment global loads hoisted ABOVE W staging so their HBM/L3
// latency hides under the W split + LDS writes + barrier.
// 3-term split product; frag maps per m89 (proven rounds 3-7).
// ===========================================================================
template <int T, bool INF32, bool OUTF32, bool RELU>
__global__ __launch_bounds__(512, 4) void gemm3_kernel(const void* __restrict__ Ah_,
                                                       const void* __restrict__ Al_,
                                                       const float* __restrict__ Wg,
                                                       const float* __restrict__ Bg,
                                                       __bf16* __restrict__ Ohi,
                                                       __bf16* __restrict__ Olo,
                                                       float* __restrict__ Of32) {
    constexpr int WFB = 2 * T * 4 * 64 * 8 * 2;               // wf bytes (64KB @ T=8)
    constexpr int SMB = OUTF32 ? WFB : (WFB > 128 * 132 * 4 ? WFB : 128 * 132 * 4);
    __shared__ __align__(16) char smem[SMB];
    __bf16 (*wf)[T][4][64][8] = (__bf16(*)[T][4][64][8])smem;  // [plane][t][ks][lane][8]
    u32* obuf = (u32*)smem;                                     // [128][132] aliased

    const int tid = threadIdx.x;
    const int lane = tid & 63, w = tid >> 6;
    const int lm = lane & 15, g = lane >> 4;
    const int tile = blockIdx.x;

    // ---- A loads FIRST (independent of W; latency hides under W-stage) ----
    const int arow = tile * 128 + w * 16 + lm;
    bf16x8 ah[4], al[4];
    float tv[4][8];
    if (INF32) {
        const float* base = (const float*)Ah_ + (size_t)min(arow, NNODES - 1) * 128;
#pragma unroll
        for (int ks = 0; ks < 4; ++ks) {
            *(float4*)&tv[ks][0] = *(const float4*)(base + ks * 32 + g * 8);
            *(float4*)&tv[ks][4] = *(const float4*)(base + ks * 32 + g * 8 + 4);
        }
    } else {
        const __bf16* bh = (const __bf16*)Ah_ + (size_t)arow * 128;
        const __bf16* bl = (const __bf16*)Al_ + (size_t)arow * 128;
#pragma unroll
        for (int ks = 0; ks < 4; ++ks) {
            ah[ks] = *(const bf16x8*)(bh + ks * 32 + g * 8);
            al[ks] = *(const bf16x8*)(bl + ks * 32 + g * 8);
        }
    }
    float bval[T];
#pragma unroll
    for (int t = 0; t < T; ++t) bval[t] = Bg[t * 16 + lm];

    // ---- stage W (fp32) -> LDS hi/lo fragments ----
    for (int c = tid; c < T * 4 * 64; c += 512) {
        int t = c >> 8;
        int ks = (c >> 6) & 3;
        int ln = c & 63;
        int n = t * 16 + (ln & 15);
        int k0 = ks * 32 + (ln >> 4) * 8;
        const float* srcp = Wg + (size_t)n * 128 + k0;
        float wv[8];
        *(float4*)wv = *(const float4*)srcp;
        *(float4*)(wv + 4) = *(const float4*)(srcp + 4);
        bf16x8 h, l;
        split8(wv, h, l);
        *(bf16x8*)&wf[0][t][ks][ln][0] = h;
        *(bf16x8*)&wf[1][t][ks][ln][0] = l;
    }
    __syncthreads();

    if (INF32) {
#pragma unroll
        for (int ks = 0; ks < 4; ++ks) split8(tv[ks], ah[ks], al[ks]);
    }

    // ---- MFMA: T independent chains ----
    f32x4 acc[T];
#pragma unroll
    for (int t = 0; t < T; ++t) acc[t] = (f32x4){bval[t], bval[t], bval[t], bval[t]};
#pragma unroll
    for (int t = 0; t < T; ++t) {
#pragma unroll
        for (int ks = 0; ks < 4; ++ks) {
            bf16x8 wh = *(const bf16x8*)&wf[0][t][ks][lane][0];
            bf16x8 wl = *(const bf16x8*)&wf[1][t][ks][lane][0];
            acc[t] = __builtin_amdgcn_mfma_f32_16x16x32_bf16(ah[ks], wh, acc[t], 0, 0, 0);
            acc[t] = __builtin_amdgcn_mfma_f32_16x16x32_bf16(al[ks], wh, acc[t], 0, 0, 0);
            acc[t] = __builtin_amdgcn_mfma_f32_16x16x32_bf16(ah[ks], wl, acc[t], 0, 0, 0);
        }
    }

    if (OUTF32) {
        // direct f32 stores: per (t,r) instruction = 4 rows x 64B full lines
        const int mrow0 = tile * 128 + w * 16 + g * 4;
#pragma unroll
        for (int t = 0; t < T; ++t) {
            const int n = t * 16 + lm;
#pragma unroll
            for (int r = 0; r < 4; ++r) {
                float v = acc[t][r];
                if (RELU) v = fmaxf(v, 0.f);
                int m = mrow0 + r;
                if (m < NNODES) Of32[(size_t)m * 64 + n] = v;
            }
        }
        return;
    }

    // ---- staged epilogue: acc -> obuf (u32 packed) -> full-line plane stores
    __syncthreads();  // all waves done with wf before alias
    {
        const int lrow0 = w * 16 + g * 4;
#pragma unroll
        for (int t = 0; t < T; ++t) {
            const int col = t * 16 + lm;
#pragma unroll
            for (int r = 0; r < 4; ++r) {
                float v = acc[t][r];
                if (RELU) v = fmaxf(v, 0.f);
                __bf16 h = (__bf16)v;
                __bf16 l = (__bf16)(v - (float)h);
                unsigned short hs = *(unsigned short*)&h;
                unsigned short ls = *(unsigned short*)&l;
                obuf[(lrow0 + r) * 132 + col] = ((u32)ls << 16) | (u32)hs;
            }
        }
    }
    __syncthreads();
#pragma unroll
    for (int pass = 0; pass < 4; ++pass) {
        int unit = pass * 512 + tid;   // 0..2047
        int lrow = unit >> 4;          // 0..127
        int c8 = unit & 15;            // 16B chunk (8 cols)
        const u32* p = obuf + lrow * 132 + c8 * 8;
        u32 v[8];
        *(f32x4*)v = *(const f32x4*)p;
        *(f32x4*)(v + 4) = *(const f32x4*)(p + 4);
        bf16x8 hh, ll;
#pragma unroll
        for (int j = 0; j < 8; ++j) {
            unsigned short hs = (unsigned short)(v[j] & 0xffffu);
            unsigned short ls = (unsigned short)(v[j] >> 16);
            hh[j] = *(__bf16*)&hs;
            ll[j] = *(__bf16*)&ls;
        }
        size_t off = (size_t)(tile * 128 + lrow) * 128 + c8 * 8;
        *(bf16x8*)(Ohi + off) = hh;
        *(bf16x8*)(Olo + off) = ll;
    }
}

// ===========================================================================
extern "C" void kernel_launch(void* const* d_in, const int* in_sizes, int n_in,
                              void* d_out, int out_size, void* d_ws, size_t ws_size,
                              hipStream_t stream) {
    const float* x   = (const float*)d_in[0];
    const int*   src = (const int*)d_in[1];
    const int*   dst = (const int*)d_in[2];
    const float* W1  = (const float*)d_in[3];
    const float* b1  = (const float*)d_in[4];
    const float* W2  = (const float*)d_in[5];
    const float* b2  = (const float*)d_in[6];
    const float* W3  = (const float*)d_in[7];
    const float* b3  = (const float*)d_in[8];
    const float* Wo1 = (const float*)d_in[9];
    const float* bo1 = (const float*)d_in[10];
    const float* Wo2 = (const float*)d_in[11];
    const float* bo2 = (const float*)d_in[12];
    float* out = (float*)d_out;

    const size_t PLANE = (size_t)NROWPAD * 128 * sizeof(__bf16);  // 25.62 MB
    char* ws = (char*)d_ws;
    __bf16* P0h = (__bf16*)ws;
    __bf16* P0l = (__bf16*)(ws + PLANE);
    __bf16* P1h = (__bf16*)(ws + 2 * PLANE);
    __bf16* P1l = (__bf16*)(ws + 3 * PLANE);
    char* p = ws + 4 * PLANE;
    int* counts = (int*)p;  p += 512 * 1024;
    int* rowptr = (int*)p;  p += 512 * 1024;
    int* bsum   = (int*)p;  p += 16 * 1024;
    int* eidx   = (int*)p;  // 3.2 MB

    dim3 blk(256);
    const int NB = (NNODES + 255) / 256;  // 391
    const int ge = (NEDGES + 255) / 256;  // 3125
    const int gg = (NNODES + 3) / 4;      // 25000

    // ---- CSR build (dst-indexed) ----
    hipMemsetAsync(counts, 0, NNODES * sizeof(int), stream);
    hist_kernel<<<ge, blk, 0, stream>>>(dst, counts, NEDGES);
    scan1_kernel<<<NB, blk, 0, stream>>>(counts, bsum, NNODES);
    scan2_kernel<<<1, 512, 0, stream>>>(bsum, NB);
    scan3_kernel<<<NB, blk, 0, stream>>>(counts, bsum, rowptr, NNODES);
    fill_kernel<<<ge, blk, 0, stream>>>(src, dst, rowptr, counts, eidx, NEDGES);

    // ---- x2 = lin2(relu(lin1(x))) ----
    gemm3_kernel<8, true,  false, true ><<<NTILE128, 512, 0, stream>>>(x, nullptr, W1, b1, P0h, P0l, nullptr);
    gemm3_kernel<8, false, false, false><<<NTILE128, 512, 0, stream>>>(P0h, P0l, W2, b2, P1h, P1l, nullptr);

    // ---- h = x2 + mean_agg(x2) ----
    gather_kernel<<<gg, blk, 0, stream>>>(P1h, P1l, rowptr, eidx, P0h, P0l, NNODES);

    // ---- h = lin2(relu(lin1(h))); h3 = relu(lin3(h)) ----
    gemm3_kernel<8, false, false, true ><<<NTILE128, 512, 0, stream>>>(P0h, P0l, W1, b1, P1h, P1l, nullptr);
    gemm3_kernel<8, false, false, false><<<NTILE128, 512, 0, stream>>>(P1h, P1l, W2, b2, P0h, P0l, nullptr);
    gemm3_kernel<8, false, false, true ><<<NTILE128, 512, 0, stream>>>(P0h, P0l, W3, b3, P1h, P1l, nullptr);

    // ---- h4 = h3 + mean_agg(h3) ----
    gather_kernel<<<gg, blk, 0, stream>>>(P1h, P1l, rowptr, eidx, P0h, P0l, NNODES);

    // ---- h5 = relu(lin3(h4)); h6 = relu(lino1(h5)); out = lino2(h6) ----
    gemm3_kernel<8, false, false, true ><<<NTILE128, 512, 0, stream>>>(P0h, P0l, W3, b3, P1h, P1l, nullptr);
    gemm3_kernel<8, false, false, true ><<<NTILE128, 512, 0, stream>>>(P1h, P1l, Wo1, bo1, P0h, P0l, nullptr);
    gemm3_kernel<4, false, true,  false><<<NTILE128, 512, 0, stream>>>(P0h, P0l, Wo2, bo2, nullptr, nullptr, out);
}

// Round 9
// 424.623 us; speedup vs baseline: 3.4550x; 1.1731x over previous
//
#include <hip/hip_runtime.h>

#define NNODES 100000
#define NEDGES 800000
#define NTILE128 782            // ceil(100000/128)
#define NROWPAD (NTILE128*128)  // 100096 padded rows in ws planes

typedef _Float16 f16x8 __attribute__((ext_vector_type(8)));
typedef float    f32x4 __attribute__((ext_vector_type(4)));
typedef unsigned int u32;
typedef unsigned short u16;

// ===========================================================================
// CSR build (round-3 proven)
// ===========================================================================
__global__ __launch_bounds__(256) void hist_kernel(const int* __restrict__ dst,
                                                   int* __restrict__ counts, int nE) {
    int i = blockIdx.x * 256 + threadIdx.x;
    if (i < nE) atomicAdd(counts + dst[i], 1);
}

__global__ __launch_bounds__(256) void scan1_kernel(const int* __restrict__ counts,
                                                    int* __restrict__ bsum, int n) {
    __shared__ int s[256];
    int i = blockIdx.x * 256 + threadIdx.x;
    s[threadIdx.x] = (i < n) ? counts[i] : 0;
    __syncthreads();
    for (int off = 128; off > 0; off >>= 1) {
        if (threadIdx.x < off) s[threadIdx.x] += s[threadIdx.x + off];
        __syncthreads();
    }
    if (threadIdx.x == 0) bsum[blockIdx.x] = s[0];
}

__global__ __launch_bounds__(512) void scan2_kernel(int* __restrict__ bsum, int nb) {
    __shared__ int s[512];
    int t = threadIdx.x;
    int orig = (t < nb) ? bsum[t] : 0;
    s[t] = orig;
    __syncthreads();
    for (int off = 1; off < 512; off <<= 1) {
        int v = (t >= off) ? s[t - off] : 0;
        __syncthreads();
        s[t] += v;
        __syncthreads();
    }
    if (t < nb) bsum[t] = s[t] - orig;  // exclusive
}

__global__ __launch_bounds__(256) void scan3_kernel(int* __restrict__ counts,
                                                    const int* __restrict__ boff,
                                                    int* __restrict__ rowptr, int n) {
    __shared__ int s[256];
    int i = blockIdx.x * 256 + threadIdx.x;
    int t = threadIdx.x;
    int orig = (i < n) ? counts[i] : 0;
    s[t] = orig;
    __syncthreads();
    for (int off = 1; off < 256; off <<= 1) {
        int v = (t >= off) ? s[t - off] : 0;
        __syncthreads();
        s[t] += v;
        __syncthreads();
    }
    if (i < n) {
        rowptr[i] = boff[blockIdx.x] + s[t] - orig;
        counts[i] = 0;  // reused as fill cursor
    }
    if (i == n - 1) rowptr[n] = boff[blockIdx.x] + s[t];
}

__global__ __launch_bounds__(256) void fill_kernel(const int* __restrict__ src,
                                                   const int* __restrict__ dst,
                                                   const int* __restrict__ rowptr,
                                                   int* __restrict__ cur,
                                                   int* __restrict__ eidx, int nE) {
    int i = blockIdx.x * 256 + threadIdx.x;
    if (i >= nE) return;
    int d = dst[i];
    int p = atomicAdd(cur + d, 1);
    eidx[rowptr[d] + p] = src[i];
}

// ===========================================================================
// Gather-mean + combine (single fp16 plane): out = base + mean_nbr H[nbr].
// One wave/node; 8 edges in flight (round-8 proven); 16 lanes x f16x8 per row.
// ===========================================================================
__global__ __launch_bounds__(256) void gather_kernel(const _Float16* __restrict__ H,
                                                     const int* __restrict__ rowptr,
                                                     const int* __restrict__ eidx,
                                                     _Float16* __restrict__ O, int n) {
    int node = blockIdx.x * 4 + (threadIdx.x >> 6);
    int lane = threadIdx.x & 63;
    if (node >= n) return;
    int g = lane >> 4, p = lane & 15;
    int e0 = rowptr[node], e1 = rowptr[node + 1];
    float acc[8] = {0.f, 0.f, 0.f, 0.f, 0.f, 0.f, 0.f, 0.f};
    for (int j = e0; j < e1; j += 8) {
        int na = e1 - j;
        int sid = (lane < 8 && lane < na) ? eidx[j + lane] : -1;
        int s0 = __shfl(sid, g);        // edge slot g
        int s1 = __shfl(sid, g + 4);    // edge slot g+4
        f16x8 v0, v1;
        bool h0 = (s0 >= 0), h1 = (s1 >= 0);
        if (h0) v0 = *(const f16x8*)(H + (size_t)s0 * 128 + p * 8);
        if (h1) v1 = *(const f16x8*)(H + (size_t)s1 * 128 + p * 8);
        if (h0) {
#pragma unroll
            for (int r = 0; r < 8; ++r) acc[r] += (float)v0[r];
        }
        if (h1) {
#pragma unroll
            for (int r = 0; r < 8; ++r) acc[r] += (float)v1[r];
        }
    }
#pragma unroll
    for (int r = 0; r < 8; ++r) {
        acc[r] += __shfl_xor(acc[r], 16);
        acc[r] += __shfl_xor(acc[r], 32);
    }
    if (g == 0) {
        float rinv = 1.0f / fmaxf((float)(e1 - e0), 1.0f);
        f16x8 b = *(const f16x8*)(H + (size_t)node * 128 + p * 8);
        f16x8 o;
#pragma unroll
        for (int r = 0; r < 8; ++r) o[r] = (_Float16)((float)b[r] + acc[r] * rinv);
        *(f16x8*)(O + (size_t)node * 128 + p * 8) = o;
    }
}

// ===========================================================================
// gemm4 (fp16 single-plane): out[M,N] = act(in[M,128] @ W[N,128]^T + b),
// N = T*16 (128 or 64). One-shot blocks: grid = NTILE128; 512 thr = 8 waves;
// wave w owns rows [tile*128+16w, +16) x ALL N cols (T independent chains).
// mfma_f32_16x16x32_f16, 1 MFMA per (t,ks) — same fragment maps as the
// bf16 path proven rounds 3-8 (shape-determined, dtype-independent).
// W cast fp32->fp16 into 32KB LDS fragpack; A-loads hoisted above W-stage.
// Epilogue: round-7-proven staged path (u32 obuf -> full-line f16x8 stores).
// ===========================================================================
template <int T, bool INF32, bool OUTF32, bool RELU>
__global__ __launch_bounds__(512, 4) void gemm4_kernel(const void* __restrict__ A_,
                                                       const float* __restrict__ Wg,
                                                       const float* __restrict__ Bg,
                                                       _Float16* __restrict__ O,
                                                       float* __restrict__ Of32) {
    constexpr int WFB = T * 4 * 64 * 8 * 2;                    // 32KB @ T=8
    constexpr int OBB = 128 * 132 * 4;                         // 67.6KB
    constexpr int SMB = OUTF32 ? WFB : (WFB > OBB ? WFB : OBB);
    __shared__ __align__(16) char smem[SMB];
    _Float16 (*wf)[4][64][8] = (_Float16(*)[4][64][8])smem;    // [t][ks][lane][8]
    u32* obuf = (u32*)smem;                                    // [128][132] aliased

    const int tid = threadIdx.x;
    const int lane = tid & 63, w = tid >> 6;
    const int lm = lane & 15, g = lane >> 4;
    const int tile = blockIdx.x;

    // ---- A loads FIRST (latency hides under W-stage; round-8) ----
    const int arow = tile * 128 + w * 16 + lm;
    f16x8 ah[4];
    float tv[4][8];
    if (INF32) {
        const float* base = (const float*)A_ + (size_t)min(arow, NNODES - 1) * 128;
#pragma unroll
        for (int ks = 0; ks < 4; ++ks) {
            *(float4*)&tv[ks][0] = *(const float4*)(base + ks * 32 + g * 8);
            *(float4*)&tv[ks][4] = *(const float4*)(base + ks * 32 + g * 8 + 4);
        }
    } else {
        const _Float16* bp = (const _Float16*)A_ + (size_t)arow * 128;
#pragma unroll
        for (int ks = 0; ks < 4; ++ks) ah[ks] = *(const f16x8*)(bp + ks * 32 + g * 8);
    }
    float bval[T];
#pragma unroll
    for (int t = 0; t < T; ++t) bval[t] = Bg[t * 16 + lm];

    // ---- stage W (fp32) -> LDS fp16 fragments ----
    for (int c = tid; c < T * 4 * 64; c += 512) {
        int t = c >> 8;
        int ks = (c >> 6) & 3;
        int ln = c & 63;
        int n = t * 16 + (ln & 15);
        int k0 = ks * 32 + (ln >> 4) * 8;
        const float* srcp = Wg + (size_t)n * 128 + k0;
        float wv[8];
        *(float4*)wv = *(const float4*)srcp;
        *(float4*)(wv + 4) = *(const float4*)(srcp + 4);
        f16x8 hv;
#pragma unroll
        for (int j = 0; j < 8; ++j) hv[j] = (_Float16)wv[j];
        *(f16x8*)&wf[t][ks][ln][0] = hv;
    }
    __syncthreads();

    if (INF32) {
#pragma unroll
        for (int ks = 0; ks < 4; ++ks)
#pragma unroll
            for (int j = 0; j < 8; ++j) ah[ks][j] = (_Float16)tv[ks][j];
    }

    // ---- MFMA: T independent chains ----
    f32x4 acc[T];
#pragma unroll
    for (int t = 0; t < T; ++t) acc[t] = (f32x4){bval[t], bval[t], bval[t], bval[t]};
#pragma unroll
    for (int t = 0; t < T; ++t) {
#pragma unroll
        for (int ks = 0; ks < 4; ++ks) {
            f16x8 wh = *(const f16x8*)&wf[t][ks][lane][0];
            acc[t] = __builtin_amdgcn_mfma_f32_16x16x32_f16(ah[ks], wh, acc[t], 0, 0, 0);
        }
    }

    if (OUTF32) {
        // direct f32 stores: per (t,r) instruction = 4 rows x 64B full lines
        const int mrow0 = tile * 128 + w * 16 + g * 4;
#pragma unroll
        for (int t = 0; t < T; ++t) {
            const int n = t * 16 + lm;
#pragma unroll
            for (int r = 0; r < 4; ++r) {
                float v = acc[t][r];
                if (RELU) v = fmaxf(v, 0.f);
                int m = mrow0 + r;
                if (m < NNODES) Of32[(size_t)m * 64 + n] = v;
            }
        }
        return;
    }

    // ---- staged epilogue: acc -> obuf (u32, low16 = fp16) -> full-line stores
    __syncthreads();  // all waves done with wf before alias
    {
        const int lrow0 = w * 16 + g * 4;
#pragma unroll
        for (int t = 0; t < T; ++t) {
            const int col = t * 16 + lm;
#pragma unroll
            for (int r = 0; r < 4; ++r) {
                float v = acc[t][r];
                if (RELU) v = fmaxf(v, 0.f);
                _Float16 h = (_Float16)v;
                obuf[(lrow0 + r) * 132 + col] = (u32)(*(u16*)&h);
            }
        }
    }
    __syncthreads();
#pragma unroll
    for (int pass = 0; pass < 4; ++pass) {
        int unit = pass * 512 + tid;   // 0..2047
        int lrow = unit >> 4;          // 0..127
        int c8 = unit & 15;            // 8-col chunk
        const u32* p = obuf + lrow * 132 + c8 * 8;
        u32 v[8];
        *(f32x4*)v = *(const f32x4*)p;
        *(f32x4*)(v + 4) = *(const f32x4*)(p + 4);
        f16x8 hh;
#pragma unroll
        for (int j = 0; j < 8; ++j) {
            u16 hs = (u16)(v[j] & 0xffffu);
            hh[j] = *(_Float16*)&hs;
        }
        size_t off = (size_t)(tile * 128 + lrow) * 128 + c8 * 8;
        *(f16x8*)(O + off) = hh;
    }
}

// ===========================================================================
extern "C" void kernel_launch(void* const* d_in, const int* in_sizes, int n_in,
                              void* d_out, int out_size, void* d_ws, size_t ws_size,
                              hipStream_t stream) {
    const float* x   = (const float*)d_in[0];
    const int*   src = (const int*)d_in[1];
    const int*   dst = (const int*)d_in[2];
    const float* W1  = (const float*)d_in[3];
    const float* b1  = (const float*)d_in[4];
    const float* W2  = (const float*)d_in[5];
    const float* b2  = (const float*)d_in[6];
    const float* W3  = (const float*)d_in[7];
    const float* b3  = (const float*)d_in[8];
    const float* Wo1 = (const float*)d_in[9];
    const float* bo1 = (const float*)d_in[10];
    const float* Wo2 = (const float*)d_in[11];
    const float* bo2 = (const float*)d_in[12];
    float* out = (float*)d_out;

    const size_t PLANE = (size_t)NROWPAD * 128 * sizeof(_Float16);  // 25.62 MB
    char* ws = (char*)d_ws;
    _Float16* P0 = (_Float16*)ws;
    _Float16* P1 = (_Float16*)(ws + PLANE);
    char* p = ws + 2 * PLANE;
    int* counts = (int*)p;  p += 512 * 1024;
    int* rowptr = (int*)p;  p += 512 * 1024;
    int* bsum   = (int*)p;  p += 16 * 1024;
    int* eidx   = (int*)p;  // 3.2 MB

    dim3 blk(256);
    const int NB = (NNODES + 255) / 256;  // 391
    const int ge = (NEDGES + 255) / 256;  // 3125
    const int gg = (NNODES + 3) / 4;      // 25000

    // ---- CSR build (dst-indexed) ----
    hipMemsetAsync(counts, 0, NNODES * sizeof(int), stream);
    hist_kernel<<<ge, blk, 0, stream>>>(dst, counts, NEDGES);
    scan1_kernel<<<NB, blk, 0, stream>>>(counts, bsum, NNODES);
    scan2_kernel<<<1, 512, 0, stream>>>(bsum, NB);
    scan3_kernel<<<NB, blk, 0, stream>>>(counts, bsum, rowptr, NNODES);
    fill_kernel<<<ge, blk, 0, stream>>>(src, dst, rowptr, counts, eidx, NEDGES);

    // ---- x2 = lin2(relu(lin1(x))) ----
    gemm4_kernel<8, true,  false, true ><<<NTILE128, 512, 0, stream>>>(x,  W1, b1, P0, nullptr);
    gemm4_kernel<8, false, false, false><<<NTILE128, 512, 0, stream>>>(P0, W2, b2, P1, nullptr);

    // ---- h = x2 + mean_agg(x2) ----
    gather_kernel<<<gg, blk, 0, stream>>>(P1, rowptr, eidx, P0, NNODES);

    // ---- h = lin2(relu(lin1(h))); h3 = relu(lin3(h)) ----
    gemm4_kernel<8, false, false, true ><<<NTILE128, 512, 0, stream>>>(P0, W1, b1, P1, nullptr);
    gemm4_kernel<8, false, false, false><<<NTILE128, 512, 0, stream>>>(P1, W2, b2, P0, nullptr);
    gemm4_kernel<8, false, false, true ><<<NTILE128, 512, 0, stream>>>(P0, W3, b3, P1, nullptr);

    // ---- h4 = h3 + mean_agg(h3) ----
    gather_kernel<<<gg, blk, 0, stream>>>(P1, rowptr, eidx, P0, NNODES);

    // ---- h5 = relu(lin3(h4)); h6 = relu(lino1(h5)); out = lino2(h6) ----
    gemm4_kernel<8, false, false, true ><<<NTILE128, 512, 0, stream>>>(P0, W3, b3, P1, nullptr);
    gemm4_kernel<8, false, false, true ><<<NTILE128, 512, 0, stream>>>(P1, Wo1, bo1, P0, nullptr);
    gemm4_kernel<4, false, true,  false><<<NTILE128, 512, 0, stream>>>(P0, Wo2, bo2, nullptr, out);
}

// Round 10
// 386.034 us; speedup vs baseline: 3.8003x; 1.1000x over previous
//
#include <hip/hip_runtime.h>

#define NNODES 100000
#define NEDGES 800000
#define NTILE128 782            // ceil(100000/128)
#define NROWPAD (NTILE128*128)  // 100096 padded rows in ws planes

typedef _Float16 f16x8 __attribute__((ext_vector_type(8)));
typedef float    f32x4 __attribute__((ext_vector_type(4)));
typedef unsigned int u32;
typedef unsigned short u16;

// ===========================================================================
// CSR build (round-3 proven)
// ===========================================================================
__global__ __launch_bounds__(256) void hist_kernel(const int* __restrict__ dst,
                                                   int* __restrict__ counts, int nE) {
    int i = blockIdx.x * 256 + threadIdx.x;
    if (i < nE) atomicAdd(counts + dst[i], 1);
}

__global__ __launch_bounds__(256) void scan1_kernel(const int* __restrict__ counts,
                                                    int* __restrict__ bsum, int n) {
    __shared__ int s[256];
    int i = blockIdx.x * 256 + threadIdx.x;
    s[threadIdx.x] = (i < n) ? counts[i] : 0;
    __syncthreads();
    for (int off = 128; off > 0; off >>= 1) {
        if (threadIdx.x < off) s[threadIdx.x] += s[threadIdx.x + off];
        __syncthreads();
    }
    if (threadIdx.x == 0) bsum[blockIdx.x] = s[0];
}

__global__ __launch_bounds__(512) void scan2_kernel(int* __restrict__ bsum, int nb) {
    __shared__ int s[512];
    int t = threadIdx.x;
    int orig = (t < nb) ? bsum[t] : 0;
    s[t] = orig;
    __syncthreads();
    for (int off = 1; off < 512; off <<= 1) {
        int v = (t >= off) ? s[t - off] : 0;
        __syncthreads();
        s[t] += v;
        __syncthreads();
    }
    if (t < nb) bsum[t] = s[t] - orig;  // exclusive
}

__global__ __launch_bounds__(256) void scan3_kernel(int* __restrict__ counts,
                                                    const int* __restrict__ boff,
                                                    int* __restrict__ rowptr, int n) {
    __shared__ int s[256];
    int i = blockIdx.x * 256 + threadIdx.x;
    int t = threadIdx.x;
    int orig = (i < n) ? counts[i] : 0;
    s[t] = orig;
    __syncthreads();
    for (int off = 1; off < 256; off <<= 1) {
        int v = (t >= off) ? s[t - off] : 0;
        __syncthreads();
        s[t] += v;
        __syncthreads();
    }
    if (i < n) {
        rowptr[i] = boff[blockIdx.x] + s[t] - orig;
        counts[i] = 0;  // reused as fill cursor
    }
    if (i == n - 1) rowptr[n] = boff[blockIdx.x] + s[t];
}

__global__ __launch_bounds__(256) void fill_kernel(const int* __restrict__ src,
                                                   const int* __restrict__ dst,
                                                   const int* __restrict__ rowptr,
                                                   int* __restrict__ cur,
                                                   int* __restrict__ eidx, int nE) {
    int i = blockIdx.x * 256 + threadIdx.x;
    if (i >= nE) return;
    int d = dst[i];
    int p = atomicAdd(cur + d, 1);
    eidx[rowptr[d] + p] = src[i];
}

// ===========================================================================
// W pre-pack: fp32 row-major [N][128] -> fragment-ordered fp16
// wpack[t][ks][lane][8] per matrix; offsets: W1@0 W2@16384 W3@32768
// Wo1@49152 Wo2@65536 (elems). One MFMA W-operand = one 16B coalesced load.
// ===========================================================================
__global__ __launch_bounds__(256) void wpack_kernel(const float* __restrict__ W1,
                                                    const float* __restrict__ W2,
                                                    const float* __restrict__ W3,
                                                    const float* __restrict__ Wo1,
                                                    const float* __restrict__ Wo2,
                                                    _Float16* __restrict__ wp) {
    int i = blockIdx.x * 256 + threadIdx.x;  // frag-group id, 0..9215
    if (i >= 9216) return;
    const float* Wm;
    int li;
    size_t base;
    if (i < 8192) {
        int m = i >> 11;
        li = i & 2047;
        Wm = (m == 0) ? W1 : (m == 1) ? W2 : (m == 2) ? W3 : Wo1;
        base = (size_t)m * 16384;
    } else {
        li = i - 8192;
        Wm = Wo2;
        base = 65536;
    }
    int lane = li & 63;
    int n = ((li >> 8) * 16) + (lane & 15);
    int k0 = (((li >> 6) & 3) * 32) + ((lane >> 4) * 8);
    const float* s = Wm + (size_t)n * 128 + k0;
    float4 a = *(const float4*)s;
    float4 b = *(const float4*)(s + 4);
    f16x8 v;
    v[0] = (_Float16)a.x; v[1] = (_Float16)a.y; v[2] = (_Float16)a.z; v[3] = (_Float16)a.w;
    v[4] = (_Float16)b.x; v[5] = (_Float16)b.y; v[6] = (_Float16)b.z; v[7] = (_Float16)b.w;
    *(f16x8*)(wp + base + (size_t)li * 8) = v;
}

// ===========================================================================
// Gather-mean + combine (round-8/9 proven): out = base + mean_nbr H[nbr].
// One wave/node; 8 edges in flight; 16 lanes x f16x8 per row.
// ===========================================================================
__global__ __launch_bounds__(256) void gather_kernel(const _Float16* __restrict__ H,
                                                     const int* __restrict__ rowptr,
                                                     const int* __restrict__ eidx,
                                                     _Float16* __restrict__ O, int n) {
    int node = blockIdx.x * 4 + (threadIdx.x >> 6);
    int lane = threadIdx.x & 63;
    if (node >= n) return;
    int g = lane >> 4, p = lane & 15;
    int e0 = rowptr[node], e1 = rowptr[node + 1];
    float acc[8] = {0.f, 0.f, 0.f, 0.f, 0.f, 0.f, 0.f, 0.f};
    for (int j = e0; j < e1; j += 8) {
        int na = e1 - j;
        int sid = (lane < 8 && lane < na) ? eidx[j + lane] : -1;
        int s0 = __shfl(sid, g);
        int s1 = __shfl(sid, g + 4);
        f16x8 v0, v1;
        bool h0 = (s0 >= 0), h1 = (s1 >= 0);
        if (h0) v0 = *(const f16x8*)(H + (size_t)s0 * 128 + p * 8);
        if (h1) v1 = *(const f16x8*)(H + (size_t)s1 * 128 + p * 8);
        if (h0) {
#pragma unroll
            for (int r = 0; r < 8; ++r) acc[r] += (float)v0[r];
        }
        if (h1) {
#pragma unroll
            for (int r = 0; r < 8; ++r) acc[r] += (float)v1[r];
        }
    }
#pragma unroll
    for (int r = 0; r < 8; ++r) {
        acc[r] += __shfl_xor(acc[r], 16);
        acc[r] += __shfl_xor(acc[r], 32);
    }
    if (g == 0) {
        float rinv = 1.0f / fmaxf((float)(e1 - e0), 1.0f);
        f16x8 b = *(const f16x8*)(H + (size_t)node * 128 + p * 8);
        f16x8 o;
#pragma unroll
        for (int r = 0; r < 8; ++r) o[r] = (_Float16)((float)b[r] + acc[r] * rinv);
        *(f16x8*)(O + (size_t)node * 128 + p * 8) = o;
    }
}

// ===========================================================================
// Fused GEMM chain, S stages of out = act(in @ W^T + b).
// Grid = NTILE128 one-shot blocks; 512 thr = 8 waves; wave w owns the 16-row
// band [tile*128+16w, +16) across ALL cols (8 indep MFMA chains/stage).
// W: fragment-packed fp16 read DIRECT from global (L2-hot, no LDS, no spill
// -> fixes round-5 fusion failure). Inter-stage h: u32 ibuf[128][137]
// (1 col/u32, low16=fp16; stride 137 => <=2-way LDS conflicts everywhere).
// Wave reads only its own band from ibuf. Last stage: OUTF32 -> direct f32
// full-line stores; else round-7-proven staged readback -> f16x8 plane lines.
// Frag maps per m89, proven rounds 3-9. Math identical to round 9.
// ===========================================================================
template <int S, bool INF32, bool OUTF32, int TL, bool R0, bool R1, bool R2>
__global__ __launch_bounds__(512, 2) void chain_kernel(
    const void* __restrict__ A_,
    const _Float16* __restrict__ wq0, const float* __restrict__ Bg0,
    const _Float16* __restrict__ wq1, const float* __restrict__ Bg1,
    const _Float16* __restrict__ wq2, const float* __restrict__ Bg2,
    _Float16* __restrict__ O, float* __restrict__ Of32) {
    __shared__ u32 ibuf[128][137];  // 70.1 KB
    const int tid = threadIdx.x;
    const int lane = tid & 63, w = tid >> 6;
    const int lm = lane & 15, g = lane >> 4;
    const int tile = blockIdx.x;

    // ---- stage-0 A fragments ----
    f16x8 ah[4];
    const int arow = tile * 128 + w * 16 + lm;
    if (INF32) {
        const float* base = (const float*)A_ + (size_t)min(arow, NNODES - 1) * 128;
#pragma unroll
        for (int ks = 0; ks < 4; ++ks) {
            float4 a = *(const float4*)(base + ks * 32 + g * 8);
            float4 b = *(const float4*)(base + ks * 32 + g * 8 + 4);
            ah[ks][0] = (_Float16)a.x; ah[ks][1] = (_Float16)a.y;
            ah[ks][2] = (_Float16)a.z; ah[ks][3] = (_Float16)a.w;
            ah[ks][4] = (_Float16)b.x; ah[ks][5] = (_Float16)b.y;
            ah[ks][6] = (_Float16)b.z; ah[ks][7] = (_Float16)b.w;
        }
    } else {
        const _Float16* bp = (const _Float16*)A_ + (size_t)arow * 128;
#pragma unroll
        for (int ks = 0; ks < 4; ++ks) ah[ks] = *(const f16x8*)(bp + ks * 32 + g * 8);
    }

#pragma unroll
    for (int s = 0; s < S; ++s) {
        const _Float16* wq = (s == 0) ? wq0 : (s == 1) ? wq1 : wq2;
        const float* Bg = (s == 0) ? Bg0 : (s == 1) ? Bg1 : Bg2;
        const bool RELU = (s == 0) ? R0 : (s == 1) ? R1 : R2;
        const int T = (s == S - 1) ? TL : 8;

        f32x4 acc[8];
#pragma unroll
        for (int t = 0; t < 8; ++t)
            if (t < T) {
                float bv = Bg[t * 16 + lm];
                acc[t] = (f32x4){bv, bv, bv, bv};
            }
#pragma unroll
        for (int t = 0; t < 8; ++t)
            if (t < T) {
#pragma unroll
                for (int ks = 0; ks < 4; ++ks) {
                    f16x8 wv = *(const f16x8*)(wq + ((size_t)(t * 4 + ks) * 64 + lane) * 8);
                    acc[t] = __builtin_amdgcn_mfma_f32_16x16x32_f16(ah[ks], wv, acc[t], 0, 0, 0);
                }
            }

        if (s < S - 1) {
            // ---- inter-stage: acc -> ibuf -> next A-frags ----
            __syncthreads();  // prev readers done before overwrite
            const int lrow0 = w * 16 + g * 4;
#pragma unroll
            for (int t = 0; t < 8; ++t)
#pragma unroll
                for (int r = 0; r < 4; ++r) {
                    float v = acc[t][r];
                    if (RELU) v = fmaxf(v, 0.f);
                    _Float16 h = (_Float16)v;
                    ibuf[lrow0 + r][t * 16 + lm] = (u32)(*(u16*)&h);
                }
            __syncthreads();
            const u32* rp = &ibuf[w * 16 + lm][0];
#pragma unroll
            for (int ks = 0; ks < 4; ++ks) {
                u32 v[8];
                *(f32x4*)v = *(const f32x4*)(rp + ks * 32 + g * 8);
                *(f32x4*)(v + 4) = *(const f32x4*)(rp + ks * 32 + g * 8 + 4);
#pragma unroll
                for (int j = 0; j < 8; ++j) {
                    u16 hs = (u16)(v[j] & 0xffffu);
                    ah[ks][j] = *(_Float16*)&hs;
                }
            }
        } else if (OUTF32) {
            // ---- final: direct f32 stores (full 64B lines) ----
            const int mrow0 = tile * 128 + w * 16 + g * 4;
#pragma unroll
            for (int t = 0; t < TL; ++t) {
                const int n = t * 16 + lm;
#pragma unroll
                for (int r = 0; r < 4; ++r) {
                    float v = acc[t][r];
                    if (RELU) v = fmaxf(v, 0.f);
                    int m = mrow0 + r;
                    if (m < NNODES) Of32[(size_t)m * 64 + n] = v;
                }
            }
        } else {
            // ---- final: staged readback -> full-line f16x8 plane stores ----
            __syncthreads();
            const int lrow0 = w * 16 + g * 4;
#pragma unroll
            for (int t = 0; t < 8; ++t)
#pragma unroll
                for (int r = 0; r < 4; ++r) {
                    float v = acc[t][r];
                    if (RELU) v = fmaxf(v, 0.f);
                    _Float16 h = (_Float16)v;
                    ibuf[lrow0 + r][t * 16 + lm] = (u32)(*(u16*)&h);
                }
            __syncthreads();
#pragma unroll
            for (int pass = 0; pass < 4; ++pass) {
                int unit = pass * 512 + tid;  // 0..2047
                int lrow = unit >> 4, c8 = unit & 15;
                const u32* p = &ibuf[lrow][c8 * 8];
                u32 v[8];
                *(f32x4*)v = *(const f32x4*)p;
                *(f32x4*)(v + 4) = *(const f32x4*)(p + 4);
                f16x8 hh;
#pragma unroll
                for (int j = 0; j < 8; ++j) {
                    u16 hs = (u16)(v[j] & 0xffffu);
                    hh[j] = *(_Float16*)&hs;
                }
                *(f16x8*)(O + (size_t)(tile * 128 + lrow) * 128 + c8 * 8) = hh;
            }
        }
    }
}

// ===========================================================================
extern "C" void kernel_launch(void* const* d_in, const int* in_sizes, int n_in,
                              void* d_out, int out_size, void* d_ws, size_t ws_size,
                              hipStream_t stream) {
    const float* x   = (const float*)d_in[0];
    const int*   src = (const int*)d_in[1];
    const int*   dst = (const int*)d_in[2];
    const float* W1  = (const float*)d_in[3];
    const float* b1  = (const float*)d_in[4];
    const float* W2  = (const float*)d_in[5];
    const float* b2  = (const float*)d_in[6];
    const float* W3  = (const float*)d_in[7];
    const float* b3  = (const float*)d_in[8];
    const float* Wo1 = (const float*)d_in[9];
    const float* bo1 = (const float*)d_in[10];
    const float* Wo2 = (const float*)d_in[11];
    const float* bo2 = (const float*)d_in[12];
    float* out = (float*)d_out;

    const size_t PLANE = (size_t)NROWPAD * 128 * sizeof(_Float16);  // 25.62 MB
    char* ws = (char*)d_ws;
    _Float16* P0 = (_Float16*)ws;
    _Float16* P1 = (_Float16*)(ws + PLANE);
    char* p = ws + 2 * PLANE;
    int* counts = (int*)p;     p += 512 * 1024;
    int* rowptr = (int*)p;     p += 512 * 1024;
    int* bsum   = (int*)p;     p += 16 * 1024;
    _Float16* wp = (_Float16*)p;  p += 256 * 1024;  // 73728 elems packed
    int* eidx   = (int*)p;     // 3.2 MB

    dim3 blk(256);
    const int NB = (NNODES + 255) / 256;  // 391
    const int ge = (NEDGES + 255) / 256;  // 3125
    const int gg = (NNODES + 3) / 4;      // 25000

    // ---- W pre-pack (once per call) ----
    wpack_kernel<<<36, blk, 0, stream>>>(W1, W2, W3, Wo1, Wo2, wp);

    // ---- CSR build (dst-indexed) ----
    hipMemsetAsync(counts, 0, NNODES * sizeof(int), stream);
    hist_kernel<<<ge, blk, 0, stream>>>(dst, counts, NEDGES);
    scan1_kernel<<<NB, blk, 0, stream>>>(counts, bsum, NNODES);
    scan2_kernel<<<1, 512, 0, stream>>>(bsum, NB);
    scan3_kernel<<<NB, blk, 0, stream>>>(counts, bsum, rowptr, NNODES);
    fill_kernel<<<ge, blk, 0, stream>>>(src, dst, rowptr, counts, eidx, NEDGES);

    const _Float16 *q1 = wp, *q2 = wp + 16384, *q3 = wp + 32768,
                   *qo1 = wp + 49152, *qo2 = wp + 65536;

    // ---- chain A: x2 = lin2(relu(lin1(x))) ----
    chain_kernel<2, true, false, 8, true, false, false><<<NTILE128, 512, 0, stream>>>(
        x, q1, b1, q2, b2, nullptr, nullptr, P0, nullptr);

    // ---- h = x2 + mean_agg(x2) ----
    gather_kernel<<<gg, blk, 0, stream>>>(P0, rowptr, eidx, P1, NNODES);

    // ---- chain B: h3 = relu(lin3(lin2(relu(lin1(h))))) ----
    chain_kernel<3, false, false, 8, true, false, true><<<NTILE128, 512, 0, stream>>>(
        P1, q1, b1, q2, b2, q3, b3, P0, nullptr);

    // ---- h4 = h3 + mean_agg(h3) ----
    gather_kernel<<<gg, blk, 0, stream>>>(P0, rowptr, eidx, P1, NNODES);

    // ---- chain C: out = lino2(relu(lino1(relu(lin3(h4))))) ----
    chain_kernel<3, false, true, 4, true, true, false><<<NTILE128, 512, 0, stream>>>(
        P1, q3, b3, qo1, bo1, qo2, bo2, nullptr, out);
}